// Round 2
// baseline (728.588 us; speedup 1.0000x reference)
//
#include <hip/hip_runtime.h>
#include <math.h>

#define BB 16
#define TT 512
#define IND 128
#define HH 256
#define DD 8
#define EPSF 1e-5f

typedef _Float16 h2_t __attribute__((ext_vector_type(2)));
typedef _Float16 h4_t __attribute__((ext_vector_type(4)));
typedef _Float16 h8_t __attribute__((ext_vector_type(8)));
typedef float f32x4 __attribute__((ext_vector_type(4)));

#define HROW 528  // bytes per batch-row of H in LDS: 512 data + 16 pad (banks balanced)

__device__ __forceinline__ float fast_tanh2(float x) {
    // no clamp needed: e->inf gives 1, e->0 gives -1, both graceful
    const float e = __expf(2.f * x);
    return 1.f - __fdividef(2.f, e + 1.f);
}

// ---------------- K1: x_proj -> xpT2[t][j>>2][b][j&3] ----------------
// Same compute as before; store index changed to the MFMA-scan-friendly layout:
// float idx = ((t*64 + (j>>2))*16 + b)*4 + (j&3)  (one dwordx4 per (lane,mt) in K2).
__global__ __launch_bounds__(512, 4) void xproj_kernel(
    const float* __restrict__ y, const float* __restrict__ W_ih,
    const float* __restrict__ b_ih, const float* __restrict__ b_hh,
    float* __restrict__ xp)
{
    __shared__ __align__(16) float ylds[IND];
    const int tid = threadIdx.x;
    const int j = tid >> 1;
    const int k4 = (tid & 1) * 4;

    float4 w[16];
    const float* wr = W_ih + (size_t)j * IND + k4;
#pragma unroll
    for (int i = 0; i < 16; ++i) w[i] = *(const float4*)(wr + i * 8);
#pragma unroll
    for (int i = 0; i < 16; ++i)
        asm volatile("" : "+v"(w[i].x), "+v"(w[i].y), "+v"(w[i].z), "+v"(w[i].w));
    const float bias = b_ih[j] + b_hh[j];

    const int row0 = blockIdx.x * 16;
    for (int r = 0; r < 16; ++r) {
        const int row = row0 + r;
        if (tid < IND / 4) ((float4*)ylds)[tid] = ((const float4*)(y + (size_t)row * IND))[tid];
        __syncthreads();
        float a0 = 0.f, a1 = 0.f, a2 = 0.f, a3 = 0.f;
#pragma unroll
        for (int i = 0; i < 16; ++i) {
            const float4 hv = *(const float4*)(ylds + i * 8 + k4);
            a0 = fmaf(hv.x, w[i].x, a0);
            a1 = fmaf(hv.y, w[i].y, a1);
            a2 = fmaf(hv.z, w[i].z, a2);
            a3 = fmaf(hv.w, w[i].w, a3);
        }
        float acc = (a0 + a1) + (a2 + a3);
        acc += __shfl_xor(acc, 1);
        if ((tid & 1) == 0) {
            const int b = row >> 9;           // T = 512
            const int t = row & (TT - 1);
            xp[((size_t)(t * 64 + (j >> 2)) * 16 + b) * 4 + (j & 3)] = acc + bias;
        }
        __syncthreads();
    }
}

// ---------------- K2: MFMA RNN scan (block 0) + prec zero-fill (blocks 1..) ----------------
// All 16 batches in ONE block (4 waves, 1 CU): per step compute
//   Hnew^T[j,b] = tanh(Xp^T[j,b] + W_hh[j,:]·H^T[:,b])
// as D = A·B with A = W_hh (M=256, pinned: 32 h8 frags/wave = 128 VGPR),
// B = H^T (K=256, N=16 batches) re-read from LDS each step (8 ds_read_b128/lane).
// mfma_f32_16x16x32_f16 layouts: A: m=l&15, k-slot=8*(l>>4)+e; B: n=l&15, same k-slot
// (A/B k-order is self-consistent, so only m/n and the m89-verified C layout matter);
// C: n=l&15, m=(l>>4)*4+r. LDS rows (per batch) padded to 528 B: b128 read start banks
// = 4*((lr+lh)&8-1) -> all 8 bank groups evenly loaded.
__global__ __launch_bounds__(256, 1) void scan_fill_kernel(
    const float* __restrict__ xp, const float* __restrict__ W_hh,
    float* __restrict__ enc, float* __restrict__ prec)
{
    if (blockIdx.x != 0) {
        const size_t n4 = (size_t)BB * DD * TT * TT / 4;
        const f32x4 z = {0.f, 0.f, 0.f, 0.f};
        f32x4* p4 = (f32x4*)prec;
        size_t idx = (size_t)(blockIdx.x - 1) * blockDim.x + threadIdx.x;
        const size_t stride = (size_t)(gridDim.x - 1) * blockDim.x;
        for (; idx < n4; idx += stride) p4[idx] = z;
        return;
    }

    const int tid = threadIdx.x;
    const int w  = tid >> 6;   // wave 0..3: owns j in [64w, 64w+64)
    const int l  = tid & 63;
    const int lr = l & 15;     // batch (n) / A-row-within-tile
    const int lh = l >> 4;     // 0..3 k-group

    __shared__ __align__(16) char hbufA[16 * HROW];
    __shared__ __align__(16) char hbufB[16 * HROW];

    // ---- A fragments: af[mt][kt], W_hh[64w+16mt+lr][32kt+8lh+e], pinned ----
    h8_t af[4][8];
#pragma unroll
    for (int mt = 0; mt < 4; ++mt) {
        const float* wrow = W_hh + (size_t)(64 * w + 16 * mt + lr) * HH;
#pragma unroll
        for (int kt = 0; kt < 8; ++kt) {
            const float* p = wrow + 32 * kt + 8 * lh;
            const f32x4 f0 = *(const f32x4*)(p);
            const f32x4 f1 = *(const f32x4*)(p + 4);
            h8_t v;
            v[0] = (_Float16)f0[0]; v[1] = (_Float16)f0[1];
            v[2] = (_Float16)f0[2]; v[3] = (_Float16)f0[3];
            v[4] = (_Float16)f1[0]; v[5] = (_Float16)f1[1];
            v[6] = (_Float16)f1[2]; v[7] = (_Float16)f1[3];
            af[mt][kt] = v;
        }
    }
#pragma unroll
    for (int mt = 0; mt < 4; ++mt)
#pragma unroll
        for (int kt = 0; kt < 8; ++kt) {
            int4 t4 = __builtin_bit_cast(int4, af[mt][kt]);
            asm volatile("" : "+v"(t4.x), "+v"(t4.y), "+v"(t4.z), "+v"(t4.w));
            af[mt][kt] = __builtin_bit_cast(h8_t, t4);
        }

    // zero-init H buffer A (h0 = 0): 256 threads x 32B = 8KB data region
    {
        const f32x4 z = {0.f, 0.f, 0.f, 0.f};
        const int rr = tid >> 4, cc = tid & 15;
        *(f32x4*)(hbufA + rr * HROW + cc * 32)      = z;
        *(f32x4*)(hbufA + rr * HROW + cc * 32 + 16) = z;
    }

    const f32x4* xp4 = (const f32x4*)xp;
    f32x4* enc4 = (f32x4*)enc;

    const char* hrd = hbufA;
    char* hwr = hbufB;

    // t=0 xp preload (chunk idx = t*1024 + (16w+4mt+lh)*16 + lr)
    f32x4 xa[4], xb[4];
#pragma unroll
    for (int mt = 0; mt < 4; ++mt)
        xa[mt] = xp4[(size_t)((16 * w + 4 * mt + lh) * 16 + lr)];

    __syncthreads();

#define SCAN_STEP(T, XC, XN)                                                          \
    {                                                                                 \
        const int t_ = (T);                                                           \
        const int tp_ = (t_ < TT - 1) ? t_ + 1 : t_;                                  \
        _Pragma("unroll")                                                             \
        for (int mt = 0; mt < 4; ++mt)                                                \
            XN[mt] = xp4[(size_t)tp_ * 1024 + ((16 * w + 4 * mt + lh) * 16 + lr)];    \
        h8_t bf[8];                                                                   \
        _Pragma("unroll")                                                             \
        for (int kt = 0; kt < 8; ++kt)                                                \
            bf[kt] = *(const h8_t*)(hrd + lr * HROW + kt * 64 + lh * 16);             \
        _Pragma("unroll")                                                             \
        for (int mt = 0; mt < 4; ++mt) {                                              \
            f32x4 acc = {0.f, 0.f, 0.f, 0.f};                                         \
            _Pragma("unroll")                                                         \
            for (int kt = 0; kt < 8; ++kt)                                            \
                acc = __builtin_amdgcn_mfma_f32_16x16x32_f16(af[mt][kt], bf[kt],      \
                                                             acc, 0, 0, 0);          \
            f32x4 s;                                                                  \
            _Pragma("unroll")                                                         \
            for (int r = 0; r < 4; ++r) s[r] = fast_tanh2(acc[r] + XC[mt][r]);        \
            enc4[(size_t)t_ * 1024 + ((16 * w + 4 * mt + lh) * 16 + lr)] = s;         \
            h4_t hv;                                                                  \
            hv[0] = (_Float16)s[0]; hv[1] = (_Float16)s[1];                           \
            hv[2] = (_Float16)s[2]; hv[3] = (_Float16)s[3];                           \
            *(h4_t*)(hwr + lr * HROW + (64 * w + 16 * mt + 4 * lh) * 2) = hv;         \
        }                                                                             \
        asm volatile("s_waitcnt lgkmcnt(0)\n\ts_barrier" ::: "memory");               \
        { const char* tmp_ = hrd; hrd = hwr; hwr = (char*)tmp_; }                     \
    }

    for (int tb = 0; tb < TT; tb += 2) {
        SCAN_STEP(tb, xa, xb)
        SCAN_STEP(tb + 1, xb, xa)
    }
#undef SCAN_STEP
}

// ---------------- K3: heads + tridiagonal fill ----------------
// enc is now encT2[t][j>>2][b][j&3]; only the staging loop's addressing changes
// (erow layout/order is identical). The t0-1 row for t0==0 reads into the xp region
// (negative offset from enc) — garbage, discarded as before.
__global__ __launch_bounds__(256) void head_kernel(
    const float* __restrict__ enc,
    const float* __restrict__ W_mean, const float* __restrict__ b_mean,
    const float* __restrict__ W_bd, const float* __restrict__ b_bd,
    float* __restrict__ mean_out, float* __restrict__ prec)
{
    const int b = blockIdx.x >> 6;
    const int t0 = (blockIdx.x & 63) * 8;
    __shared__ __align__(16) float erow[9][HH];  // rows t0-1 .. t0+7
    __shared__ float vals[8][32];

    const int tid = threadIdx.x;
    {
        const f32x4* src = (const f32x4*)enc;
        f32x4* dst = (f32x4*)erow;
        for (int i = tid; i < 9 * 64; i += 256) {
            const int rr = i >> 6, jq = i & 63;
            const long tt = (long)(t0 - 1 + rr);
            dst[rr * 64 + jq] = src[(tt * 64 + jq) * 16 + b];
        }
    }

    const int g = tid >> 3, m = tid & 7;
    const float* wrow;
    float bias;
    if (g < 8)       { wrow = W_mean + (size_t)g * HH;      bias = b_mean[g]; }
    else if (g < 24) { wrow = W_bd + (size_t)(g - 8) * HH;  bias = b_bd[g - 8]; }
    else             { wrow = W_bd + (size_t)(g - 16) * HH; bias = b_bd[g - 16]; }

    float4 wv[8];
#pragma unroll
    for (int i = 0; i < 8; ++i) wv[i] = ((const float4*)wrow)[m * 8 + i];

    __syncthreads();

    for (int r = 0; r < 8; ++r) {
        const float* src = (g >= 24) ? erow[r] : erow[r + 1];
        float acc = 0.f;
#pragma unroll
        for (int i = 0; i < 8; ++i) {
            const float4 hv = ((const float4*)src)[m * 8 + i];
            acc += wv[i].x * hv.x + wv[i].y * hv.y + wv[i].z * hv.z + wv[i].w * hv.w;
        }
        acc += __shfl_xor(acc, 1);
        acc += __shfl_xor(acc, 2);
        acc += __shfl_xor(acc, 4);
        if (m == 0) vals[r][g] = acc + bias;
    }
    __syncthreads();

    // write phase: 256 threads = 8 r-slots x 32 lanes
    const int r = tid >> 5, s = tid & 31;
    const int t = t0 + r;
    if (s < DD) {
        mean_out[((size_t)b * TT + t) * DD + s] = vals[r][s];
    } else if (s < 2 * DD) {
        const int d = s - DD;
        const float diag = vals[r][8 + d];
        const float off  = vals[r][16 + d];
        const float offp = (t > 0) ? vals[r][24 + d] : 0.f;
        const size_t rowbase = (((size_t)b * DD + d) * TT + t) * TT;
        prec[rowbase + t] = diag * diag + offp * offp + EPSF;
        if (t < TT - 1) {
            const float sv = diag * off;
            prec[rowbase + t + 1] = sv;                                 // (t, t+1)
            prec[(((size_t)b * DD + d) * TT + (t + 1)) * TT + t] = sv;  // (t+1, t)
        }
    }
}

extern "C" void kernel_launch(void* const* d_in, const int* in_sizes, int n_in,
                              void* d_out, int out_size, void* d_ws, size_t ws_size,
                              hipStream_t stream) {
    const float* y      = (const float*)d_in[0];
    const float* W_ih   = (const float*)d_in[1];
    const float* W_hh   = (const float*)d_in[2];
    const float* b_ih   = (const float*)d_in[3];
    const float* b_hh   = (const float*)d_in[4];
    const float* W_mean = (const float*)d_in[5];
    const float* b_mean = (const float*)d_in[6];
    const float* W_bd   = (const float*)d_in[7];
    const float* b_bd   = (const float*)d_in[8];

    float* out  = (float*)d_out;
    float* mean = out;                              // B*T*D floats
    float* prec = out + (size_t)BB * TT * DD;       // B*D*T*T floats

    float* xp  = (float*)d_ws;                      // B*T*H floats = 8 MB (xpT2 layout)
    float* enc = xp + (size_t)BB * TT * HH;         // B*T*H floats = 8 MB (encT2 layout)

    xproj_kernel<<<512, 512, 0, stream>>>(y, W_ih, b_ih, b_hh, xp);
    scan_fill_kernel<<<1008, 256, 0, stream>>>(xp, W_hh, enc, prec);
    head_kernel<<<1024, 256, 0, stream>>>(enc, W_mean, b_mean, W_bd, b_bd, mean, prec);
}